// Round 1
// baseline (495.902 us; speedup 1.0000x reference)
//
#include <hip/hip_runtime.h>
#include <math.h>

#define N_NODES 80000
#define E_EDGES 1280000
#define IN_DIM  512
#define OUT_DIM 64
#define POS_DIM 8
#define NEG_SLOPE 0.01f

// ---------------- GEMM: z = h @ W_fc^T  (M=80000, N=64, K=512) ----------------
// Block: 256 threads, 64 nodes x 64 outputs tile, K chunks of 32.
__global__ __launch_bounds__(256) void gemm_z(const float* __restrict__ h,
                                              const float* __restrict__ W,
                                              float* __restrict__ z) {
    __shared__ float sh[32][68];  // [k][n], pad 68 for bank spread + 16B align
    __shared__ float sw[32][68];  // [k][j]
    const int t  = threadIdx.x;
    const int tx = t & 15;        // output group (4 j's)
    const int ty = t >> 4;        // node group (4 n's)
    const int nbase = blockIdx.x * 64;

    float acc[4][4] = {};

    const int ld_row = t >> 3;        // 0..31
    const int ld_k4  = (t & 7) * 4;   // 0,4,..,28

    for (int kc = 0; kc < IN_DIM; kc += 32) {
        #pragma unroll
        for (int rp = 0; rp < 2; ++rp) {
            const int n = ld_row + rp * 32;
            const float4 v = *(const float4*)&h[(size_t)(nbase + n) * IN_DIM + kc + ld_k4];
            sh[ld_k4 + 0][n] = v.x; sh[ld_k4 + 1][n] = v.y;
            sh[ld_k4 + 2][n] = v.z; sh[ld_k4 + 3][n] = v.w;
            const float4 w = *(const float4*)&W[(size_t)n * IN_DIM + kc + ld_k4];
            sw[ld_k4 + 0][n] = w.x; sw[ld_k4 + 1][n] = w.y;
            sw[ld_k4 + 2][n] = w.z; sw[ld_k4 + 3][n] = w.w;
        }
        __syncthreads();
        #pragma unroll
        for (int k = 0; k < 32; ++k) {
            const float4 hv = *(const float4*)&sh[k][ty * 4];
            const float4 wv = *(const float4*)&sw[k][tx * 4];
            const float hr[4] = {hv.x, hv.y, hv.z, hv.w};
            const float wr[4] = {wv.x, wv.y, wv.z, wv.w};
            #pragma unroll
            for (int r = 0; r < 4; ++r)
                #pragma unroll
                for (int c = 0; c < 4; ++c)
                    acc[r][c] += hr[r] * wr[c];
        }
        __syncthreads();
    }
    #pragma unroll
    for (int r = 0; r < 4; ++r) {
        float4 o = {acc[r][0], acc[r][1], acc[r][2], acc[r][3]};
        *(float4*)&z[(size_t)(nbase + ty * 4 + r) * OUT_DIM + tx * 4] = o;
    }
}

// ---------------- per-node attention scores ----------------
__global__ __launch_bounds__(256) void attn_scores(const float* __restrict__ z,
                                                   const float* __restrict__ pos,
                                                   const float* __restrict__ Wa,
                                                   float* __restrict__ el,
                                                   float* __restrict__ er) {
    const int n = blockIdx.x * 256 + threadIdx.x;
    if (n >= N_NODES) return;
    const float* zr = &z[(size_t)n * OUT_DIM];
    float a = 0.f, b = 0.f;
    #pragma unroll
    for (int j = 0; j < OUT_DIM; j += 4) {
        const float4 v = *(const float4*)&zr[j];
        a += v.x * Wa[j + 0] + v.y * Wa[j + 1] + v.z * Wa[j + 2] + v.w * Wa[j + 3];
        b += v.x * Wa[OUT_DIM + j + 0] + v.y * Wa[OUT_DIM + j + 1]
           + v.z * Wa[OUT_DIM + j + 2] + v.w * Wa[OUT_DIM + j + 3];
    }
    const float* pr = &pos[(size_t)n * POS_DIM];
    #pragma unroll
    for (int p = 0; p < POS_DIM; ++p) {
        a += pr[p] * Wa[2 * OUT_DIM + p];
        b += pr[p] * Wa[2 * OUT_DIM + POS_DIM + p];
    }
    el[n] = a;
    er[n] = b;
}

// ---------------- CSR build ----------------
__global__ __launch_bounds__(256) void hist_deg(const int* __restrict__ dst,
                                                int* __restrict__ deg) {
    const int e = blockIdx.x * 256 + threadIdx.x;
    if (e < E_EDGES) atomicAdd(&deg[dst[e]], 1);
}

__global__ __launch_bounds__(1024) void scan_deg(const int* __restrict__ deg,
                                                 int* __restrict__ offs,
                                                 int* __restrict__ cursor) {
    __shared__ int part[1024];
    const int t = threadIdx.x;
    const int CH = (N_NODES + 1023) / 1024;  // 79
    const int lo = t * CH;
    const int hi = min(lo + CH, N_NODES);
    int s = 0;
    for (int i = lo; i < hi; ++i) s += deg[i];
    part[t] = s;
    __syncthreads();
    for (int d = 1; d < 1024; d <<= 1) {
        int v = (t >= d) ? part[t - d] : 0;
        __syncthreads();
        part[t] += v;
        __syncthreads();
    }
    int run = (t > 0) ? part[t - 1] : 0;
    for (int i = lo; i < hi; ++i) {
        offs[i] = run;
        cursor[i] = run;
        run += deg[i];
    }
    if (t == 1023) offs[N_NODES] = part[1023];
}

__global__ __launch_bounds__(256) void scatter_edges(const int* __restrict__ src,
                                                     const int* __restrict__ dst,
                                                     int* __restrict__ cursor,
                                                     int* __restrict__ esrc) {
    const int e = blockIdx.x * 256 + threadIdx.x;
    if (e >= E_EDGES) return;
    const int d = dst[e];
    const int p = atomicAdd(&cursor[d], 1);
    esrc[p] = src[e];
}

// ---------------- edge softmax + aggregate: one wave per dst node ----------------
__global__ __launch_bounds__(256) void aggregate(const int* __restrict__ offs,
                                                 const int* __restrict__ esrc,
                                                 const float* __restrict__ el,
                                                 const float* __restrict__ er,
                                                 const float* __restrict__ z,
                                                 float* __restrict__ out) {
    const int wave = (int)((blockIdx.x * 256 + threadIdx.x) >> 6);
    const int lane = threadIdx.x & 63;
    if (wave >= N_NODES) return;
    const int d = wave;
    const int start = offs[d];
    const int end   = offs[d + 1];
    const float erd = er[d];

    // phase 1: segment max
    float m = -INFINITY;
    for (int i = start + lane; i < end; i += 64) {
        const int s = esrc[i];
        float e = el[s] + erd;
        e = e > 0.f ? e : NEG_SLOPE * e;
        m = fmaxf(m, e);
    }
    #pragma unroll
    for (int off = 32; off; off >>= 1) m = fmaxf(m, __shfl_xor(m, off));

    // phase 2: exp-sum + numerator accumulation (lane = output dim)
    float acc = 0.f;
    float dsum = 0.f;
    for (int base = start; base < end; base += 64) {
        const int cl = min(64, end - base);
        int s_i = 0;
        float ex_i = 0.f;
        if (lane < cl) {
            s_i = esrc[base + lane];
            float e = el[s_i] + erd;
            e = e > 0.f ? e : NEG_SLOPE * e;
            ex_i = __expf(e - m);
        }
        dsum += ex_i;
        for (int b = 0; b < cl; ++b) {
            const float w = __shfl(ex_i, b);
            const int s   = __shfl(s_i, b);
            acc += w * z[(size_t)s * OUT_DIM + lane];
        }
    }
    #pragma unroll
    for (int off = 32; off; off >>= 1) dsum += __shfl_xor(dsum, off);

    out[(size_t)d * OUT_DIM + lane] = (end > start) ? (acc / dsum) : 0.f;
}

// ---------------- launch ----------------
extern "C" void kernel_launch(void* const* d_in, const int* in_sizes, int n_in,
                              void* d_out, int out_size, void* d_ws, size_t ws_size,
                              hipStream_t stream) {
    const float* h   = (const float*)d_in[0];
    const float* pos = (const float*)d_in[1];
    const int* src   = (const int*)d_in[2];
    const int* dst   = (const int*)d_in[3];
    const float* Wfc = (const float*)d_in[4];
    const float* Wa  = (const float*)d_in[5];
    float* out = (float*)d_out;

    char* ws = (char*)d_ws;
    float* z      = (float*)(ws);                                   // N*64 f32
    float* el     = (float*)(ws + 20480000);                        // N f32
    float* er     = (float*)(ws + 20800000);                        // N f32
    int*   deg    = (int*)  (ws + 21120000);                        // N int
    int*   offs   = (int*)  (ws + 21440000);                        // (N+1) int
    int*   cursor = (int*)  (ws + 21760004);                        // N int
    int*   esrc   = (int*)  (ws + 22080004);                        // E int

    gemm_z<<<N_NODES / 64, 256, 0, stream>>>(h, Wfc, z);
    attn_scores<<<(N_NODES + 255) / 256, 256, 0, stream>>>(z, pos, Wa, el, er);
    hipMemsetAsync(deg, 0, N_NODES * sizeof(int), stream);
    hist_deg<<<E_EDGES / 256, 256, 0, stream>>>(dst, deg);
    scan_deg<<<1, 1024, 0, stream>>>(deg, offs, cursor);
    scatter_edges<<<E_EDGES / 256, 256, 0, stream>>>(src, dst, cursor, esrc);
    aggregate<<<N_NODES / 4, 256, 0, stream>>>(offs, esrc, el, er, z, out);
}

// Round 2
// 336.498 us; speedup vs baseline: 1.4737x; 1.4737x over previous
//
#include <hip/hip_runtime.h>
#include <math.h>

#define N_NODES 80000
#define E_EDGES 1280000
#define IN_DIM  512
#define OUT_DIM 64
#define POS_DIM 8
#define NEG_SLOPE 0.01f

#define SCAN_CHUNK 1024
#define SCAN_NB    79   // ceil(80000/1024)

// ---------------- GEMM: z = h @ W_fc^T  (M=80000, N=64, K=512) ----------------
__global__ __launch_bounds__(256) void gemm_z(const float* __restrict__ h,
                                              const float* __restrict__ W,
                                              float* __restrict__ z) {
    __shared__ float sh[32][68];
    __shared__ float sw[32][68];
    const int t  = threadIdx.x;
    const int tx = t & 15;
    const int ty = t >> 4;
    const int nbase = blockIdx.x * 64;

    float acc[4][4] = {};

    const int ld_row = t >> 3;
    const int ld_k4  = (t & 7) * 4;

    for (int kc = 0; kc < IN_DIM; kc += 32) {
        #pragma unroll
        for (int rp = 0; rp < 2; ++rp) {
            const int n = ld_row + rp * 32;
            const float4 v = *(const float4*)&h[(size_t)(nbase + n) * IN_DIM + kc + ld_k4];
            sh[ld_k4 + 0][n] = v.x; sh[ld_k4 + 1][n] = v.y;
            sh[ld_k4 + 2][n] = v.z; sh[ld_k4 + 3][n] = v.w;
            const float4 w = *(const float4*)&W[(size_t)n * IN_DIM + kc + ld_k4];
            sw[ld_k4 + 0][n] = w.x; sw[ld_k4 + 1][n] = w.y;
            sw[ld_k4 + 2][n] = w.z; sw[ld_k4 + 3][n] = w.w;
        }
        __syncthreads();
        #pragma unroll
        for (int k = 0; k < 32; ++k) {
            const float4 hv = *(const float4*)&sh[k][ty * 4];
            const float4 wv = *(const float4*)&sw[k][tx * 4];
            const float hr[4] = {hv.x, hv.y, hv.z, hv.w};
            const float wr[4] = {wv.x, wv.y, wv.z, wv.w};
            #pragma unroll
            for (int r = 0; r < 4; ++r)
                #pragma unroll
                for (int c = 0; c < 4; ++c)
                    acc[r][c] += hr[r] * wr[c];
        }
        __syncthreads();
    }
    #pragma unroll
    for (int r = 0; r < 4; ++r) {
        float4 o = {acc[r][0], acc[r][1], acc[r][2], acc[r][3]};
        *(float4*)&z[(size_t)(nbase + ty * 4 + r) * OUT_DIM + tx * 4] = o;
    }
}

// ---------------- per-node attention scores ----------------
__global__ __launch_bounds__(256) void attn_scores(const float* __restrict__ z,
                                                   const float* __restrict__ pos,
                                                   const float* __restrict__ Wa,
                                                   float* __restrict__ el,
                                                   float* __restrict__ er) {
    const int n = blockIdx.x * 256 + threadIdx.x;
    if (n >= N_NODES) return;
    const float* zr = &z[(size_t)n * OUT_DIM];
    float a = 0.f, b = 0.f;
    #pragma unroll
    for (int j = 0; j < OUT_DIM; j += 4) {
        const float4 v = *(const float4*)&zr[j];
        a += v.x * Wa[j + 0] + v.y * Wa[j + 1] + v.z * Wa[j + 2] + v.w * Wa[j + 3];
        b += v.x * Wa[OUT_DIM + j + 0] + v.y * Wa[OUT_DIM + j + 1]
           + v.z * Wa[OUT_DIM + j + 2] + v.w * Wa[OUT_DIM + j + 3];
    }
    const float* pr = &pos[(size_t)n * POS_DIM];
    #pragma unroll
    for (int p = 0; p < POS_DIM; ++p) {
        a += pr[p] * Wa[2 * OUT_DIM + p];
        b += pr[p] * Wa[2 * OUT_DIM + POS_DIM + p];
    }
    el[n] = a;
    er[n] = b;
}

// ---------------- CSR build ----------------
__global__ __launch_bounds__(256) void hist_deg(const int* __restrict__ dst,
                                                int* __restrict__ deg) {
    const int e = blockIdx.x * 256 + threadIdx.x;
    if (e < E_EDGES) atomicAdd(&deg[dst[e]], 1);
}

// two-level scan: (1) per-1024-chunk sums
__global__ __launch_bounds__(256) void scan_part(const int* __restrict__ deg,
                                                 int* __restrict__ part) {
    const int b = blockIdx.x;
    const int t = threadIdx.x;
    const int idx0 = b * SCAN_CHUNK + t * 4;
    const int4 v4 = *(const int4*)&deg[idx0];  // deg padded; mask below
    int s = 0;
    s += (idx0 + 0 < N_NODES) ? v4.x : 0;
    s += (idx0 + 1 < N_NODES) ? v4.y : 0;
    s += (idx0 + 2 < N_NODES) ? v4.z : 0;
    s += (idx0 + 3 < N_NODES) ? v4.w : 0;
    #pragma unroll
    for (int off = 32; off; off >>= 1) s += __shfl_xor(s, off);
    __shared__ int ws[4];
    if ((t & 63) == 0) ws[t >> 6] = s;
    __syncthreads();
    if (t == 0) part[b] = ws[0] + ws[1] + ws[2] + ws[3];
}

// (2) exclusive scan of the 79 partials, one wave
__global__ __launch_bounds__(64) void scan_top(int* __restrict__ part) {
    const int t = threadIdx.x;
    const int i0 = 2 * t, i1 = 2 * t + 1;
    int a = (i0 < SCAN_NB) ? part[i0] : 0;
    int b = (i1 < SCAN_NB) ? part[i1] : 0;
    int s = a + b;
    #pragma unroll
    for (int off = 1; off < 64; off <<= 1) {
        int v = __shfl_up(s, off);
        if (t >= off) s += v;
    }
    const int excl = s - (a + b);
    if (i0 < SCAN_NB) part[i0] = excl;
    if (i1 < SCAN_NB) part[i1] = excl + a;
}

// (3) per-chunk local exclusive scan + global offset -> offs, cursor
__global__ __launch_bounds__(256) void scan_final(const int* __restrict__ deg,
                                                  const int* __restrict__ part,
                                                  int* __restrict__ offs,
                                                  int* __restrict__ cursor) {
    const int b = blockIdx.x;
    const int t = threadIdx.x;
    const int lane = t & 63;
    const int w = t >> 6;
    const int idx0 = b * SCAN_CHUNK + t * 4;
    const int4 v4 = *(const int4*)&deg[idx0];
    int v[4];
    v[0] = (idx0 + 0 < N_NODES) ? v4.x : 0;
    v[1] = (idx0 + 1 < N_NODES) ? v4.y : 0;
    v[2] = (idx0 + 2 < N_NODES) ? v4.z : 0;
    v[3] = (idx0 + 3 < N_NODES) ? v4.w : 0;
    const int s = v[0] + v[1] + v[2] + v[3];
    int tsum = s;
    #pragma unroll
    for (int off = 1; off < 64; off <<= 1) {
        int u = __shfl_up(tsum, off);
        if (lane >= off) tsum += u;
    }
    __shared__ int wsum[4];
    if (lane == 63) wsum[w] = tsum;
    __syncthreads();
    int woff = part[b];
    for (int i = 0; i < w; ++i) woff += wsum[i];
    int excl = woff + tsum - s;
    #pragma unroll
    for (int j = 0; j < 4; ++j) {
        const int idx = idx0 + j;
        if (idx < N_NODES) {
            offs[idx] = excl;
            cursor[idx] = excl;
            excl += v[j];
        }
    }
    if (b == 0 && t == 0) offs[N_NODES] = E_EDGES;
}

__global__ __launch_bounds__(256) void scatter_edges(const int* __restrict__ src,
                                                     const int* __restrict__ dst,
                                                     int* __restrict__ cursor,
                                                     int* __restrict__ esrc) {
    const int e = blockIdx.x * 256 + threadIdx.x;
    if (e >= E_EDGES) return;
    const int d = dst[e];
    const int p = atomicAdd(&cursor[d], 1);
    esrc[p] = src[e];
}

// ---------------- edge softmax + aggregate: one wave per dst node ----------------
__global__ __launch_bounds__(256) void aggregate(const int* __restrict__ offs,
                                                 const int* __restrict__ esrc,
                                                 const float* __restrict__ el,
                                                 const float* __restrict__ er,
                                                 const float* __restrict__ z,
                                                 float* __restrict__ out) {
    const int wave = (int)((blockIdx.x * 256 + threadIdx.x) >> 6);
    const int lane = threadIdx.x & 63;
    if (wave >= N_NODES) return;
    const int d = wave;
    const int start = offs[d];
    const int end   = offs[d + 1];
    const float erd = er[d];

    float m = -INFINITY;
    for (int i = start + lane; i < end; i += 64) {
        const int s = esrc[i];
        float e = el[s] + erd;
        e = e > 0.f ? e : NEG_SLOPE * e;
        m = fmaxf(m, e);
    }
    #pragma unroll
    for (int off = 32; off; off >>= 1) m = fmaxf(m, __shfl_xor(m, off));

    float acc = 0.f;
    float dsum = 0.f;
    for (int base = start; base < end; base += 64) {
        const int cl = min(64, end - base);
        int s_i = 0;
        float ex_i = 0.f;
        if (lane < cl) {
            s_i = esrc[base + lane];
            float e = el[s_i] + erd;
            e = e > 0.f ? e : NEG_SLOPE * e;
            ex_i = __expf(e - m);
        }
        dsum += ex_i;
        for (int b = 0; b < cl; ++b) {
            const float w = __shfl(ex_i, b);
            const int s   = __shfl(s_i, b);
            acc += w * z[(size_t)s * OUT_DIM + lane];
        }
    }
    #pragma unroll
    for (int off = 32; off; off >>= 1) dsum += __shfl_xor(dsum, off);

    out[(size_t)d * OUT_DIM + lane] = (end > start) ? (acc / dsum) : 0.f;
}

// ---------------- launch ----------------
extern "C" void kernel_launch(void* const* d_in, const int* in_sizes, int n_in,
                              void* d_out, int out_size, void* d_ws, size_t ws_size,
                              hipStream_t stream) {
    const float* h   = (const float*)d_in[0];
    const float* pos = (const float*)d_in[1];
    const int* src   = (const int*)d_in[2];
    const int* dst   = (const int*)d_in[3];
    const float* Wfc = (const float*)d_in[4];
    const float* Wa  = (const float*)d_in[5];
    float* out = (float*)d_out;

    char* ws = (char*)d_ws;
    float* z      = (float*)(ws);               // N*64 f32 = 20,480,000 B
    float* el     = (float*)(ws + 20480000);    // N f32
    float* er     = (float*)(ws + 20800000);    // N f32
    int*   deg    = (int*)  (ws + 21120000);    // padded to 81920 ints (327,680 B)
    int*   offs   = (int*)  (ws + 21447680);    // (N+1) ints, pad to 320,016 B
    int*   cursor = (int*)  (ws + 21767696);    // N ints
    int*   esrc   = (int*)  (ws + 22087696);    // E ints
    int*   part   = (int*)  (ws + 27207696);    // 128 ints

    gemm_z<<<N_NODES / 64, 256, 0, stream>>>(h, Wfc, z);
    attn_scores<<<(N_NODES + 255) / 256, 256, 0, stream>>>(z, pos, Wa, el, er);
    hipMemsetAsync(deg, 0, 81920 * sizeof(int), stream);  // include padding
    hist_deg<<<E_EDGES / 256, 256, 0, stream>>>(dst, deg);
    scan_part<<<SCAN_NB, 256, 0, stream>>>(deg, part);
    scan_top<<<1, 64, 0, stream>>>(part);
    scan_final<<<SCAN_NB, 256, 0, stream>>>(deg, part, offs, cursor);
    scatter_edges<<<E_EDGES / 256, 256, 0, stream>>>(src, dst, cursor, esrc);
    aggregate<<<N_NODES / 4, 256, 0, stream>>>(offs, esrc, el, er, z, out);
}